// Round 13
// baseline (268.591 us; speedup 1.0000x reference)
//
#include <hip/hip_runtime.h>

// Fused chunked causal attention + RoPE for MI355X (gfx950).
// B=4, SLEN=4096, H=8, ZD=128, VD=256, CHUNK=1024 -> 16 chunks x 8 heads.
// fp32 in/out; fp16 MFMA 32x32x16, fp32 accum.
// Round 13: r9 core (proven 182us) + cross-iteration DATA prefetch:
// per tile: cvt+write tile t (regs loaded last iter) -> issue tile t+1 loads
// -> barrier -> compute t. Load latency hides under compute. Only the 12 data
// vectors (48 VGPR) are prefetched; cos/sin reloaded at cvt (L2-hot table).
// One barrier/tile, dbuf, all r9 swizzles/fragment math verbatim.

#define NHEAD 8
#define ZDIM  128
#define VDIM  256
#define CHUNK 1024
#define QTILE 128   // q rows per block (4 waves x 32)
#define KT    32    // k rows per tile
#define NW    4

typedef _Float16 f16x8 __attribute__((ext_vector_type(8)));
typedef _Float16 f16x4 __attribute__((ext_vector_type(4)));
typedef __fp16   h16x2 __attribute__((ext_vector_type(2)));   // cvt_pkrtz return type
typedef float    f32x4  __attribute__((ext_vector_type(4)));
typedef float    f32x16 __attribute__((ext_vector_type(16)));
typedef unsigned int u32;

#define KSTRIDE 128   // halfs per K-lds row (256B rows; chunk^(row&7) XOR swizzle)
#define VSTRIDE 36    // halfs per V^T-lds row (32 + 4 pad)
#define LOG2E   1.44269504088896f
#define RTHR    11.5415603f   /* 8 nats in log2 domain: defer-max threshold */

__global__ __launch_bounds__(256, 2)
void attn_fused(const float* __restrict__ xq, const float* __restrict__ xk,
                const float* __restrict__ xv, const float* __restrict__ cosT,
                const float* __restrict__ sinT, float* __restrict__ out)
{
  __shared__ _Float16 Klds[2][KT * KSTRIDE];     // 16.0 KB
  __shared__ _Float16 Vlds[2][VDIM * VSTRIDE];   // 36.9 KB (transposed, swizzled)
  // total 52.9 KB -> 2 blocks/CU (register-limited to 2 anyway)

  // XCD-grouping swizzle (bijective on [0,512))
  const int b = (int)blockIdx.x;
  const int d = (b & 7) * 64 + (b >> 3);
  const int qpair = d & 3;                       // 0..3 -> q-tiles {7-qpair, qpair}
  const int ch = d >> 2;                         // 0..127
  const int h  = ch & 7;
  const int cb = ch >> 3;

  const int tid  = threadIdx.x;
  const int w    = tid >> 6;                     // wave 0..3
  const int lane = tid & 63;
  const int l31  = lane & 31;
  const int hi   = lane >> 5;                    // 0/1
  const int vswz = (l31 >> 3) & 3;               // V read kblk XOR
  const int kswz = l31 & 7;                      // K read chunk XOR (row&7)

  const size_t row0 = (size_t)cb * CHUNK;

  // staging thread mapping
  const int kr    = tid >> 3;             // K row 0..31
  const int kt8   = tid & 7;              // K chunk pair {kt8, kt8+8}
  const int vg    = tid >> 5;             // 0..7 -> V rows vg*4..+3
  const int vc0   = (tid & 31) * 8;       // V col group
  const int vsw   = tid & 3;              // V write kblk XOR
  const int vflip = ((tid >> 2) & 1) * 4; // V write sub-slot XOR ((vcol>>5)&1)*4
  const int kblk  = vg >> 1;
  const int inb   = (vg & 1) * 4;

  int buf = 0;

  // prefetch registers: tile t+1's DATA (K 16 floats, V 32 floats)
  f32x4 pk0, pk1, pk2, pk3;
  f32x4 pv0, pv1, pv2, pv3, pv4, pv5, pv6, pv7;

#define LOADT(ktb_)                                                       \
  do {                                                                    \
    const int krow_ = (ktb_) + kr;                                        \
    const float* kpb_ = xk + (row0 + krow_) * (size_t)(NHEAD * ZDIM) + h * ZDIM; \
    pk0 = *(const f32x4*)(kpb_ + 8 * kt8);                                \
    pk1 = *(const f32x4*)(kpb_ + 8 * kt8 + 4);                            \
    pk2 = *(const f32x4*)(kpb_ + 8 * kt8 + 64);                           \
    pk3 = *(const f32x4*)(kpb_ + 8 * kt8 + 68);                           \
    const int vrow_ = (ktb_) + vg * 4;                                    \
    const float* vp_ = xv + (row0 + vrow_) * (size_t)(NHEAD * VDIM) + h * VDIM + vc0; \
    pv0 = *(const f32x4*)(vp_);         pv1 = *(const f32x4*)(vp_ + 4);   \
    pv2 = *(const f32x4*)(vp_ + 2048);  pv3 = *(const f32x4*)(vp_ + 2052);\
    pv4 = *(const f32x4*)(vp_ + 4096);  pv5 = *(const f32x4*)(vp_ + 4100);\
    pv6 = *(const f32x4*)(vp_ + 6144);  pv7 = *(const f32x4*)(vp_ + 6148);\
  } while (0)

#define WRITET(ktb_)                                                      \
  do {                                                                    \
    const int krow_ = (ktb_) + kr;                                        \
    const float* ckb_ = cosT + krow_ * (ZDIM / 2);                        \
    const float* skb_ = sinT + krow_ * (ZDIM / 2);                        \
    f32x4 ca  = *(const f32x4*)(ckb_ + 4 * kt8);                          \
    f32x4 sa  = *(const f32x4*)(skb_ + 4 * kt8);                          \
    f32x4 cbv = *(const f32x4*)(ckb_ + 4 * kt8 + 32);                     \
    f32x4 sbv = *(const f32x4*)(skb_ + 4 * kt8 + 32);                     \
    union { h16x2 h2[4]; f16x8 v; } koA, koB;                             \
    _Pragma("unroll")                                                     \
    for (int p = 0; p < 4; ++p) {                                         \
      const float xrA = (p < 2 ? pk0[2 * p] : pk1[2 * p - 4]);            \
      const float xiA = (p < 2 ? pk0[2 * p + 1] : pk1[2 * p - 3]);        \
      koA.h2[p] = __builtin_amdgcn_cvt_pkrtz(xrA * ca[p] - xiA * sa[p],   \
                                             xrA * sa[p] + xiA * ca[p]);  \
      const float xrB = (p < 2 ? pk2[2 * p] : pk3[2 * p - 4]);            \
      const float xiB = (p < 2 ? pk2[2 * p + 1] : pk3[2 * p - 3]);        \
      koB.h2[p] = __builtin_amdgcn_cvt_pkrtz(xrB * cbv[p] - xiB * sbv[p], \
                                             xrB * sbv[p] + xiB * cbv[p]);\
    }                                                                     \
    const int sw_ = kr & 7;                                               \
    *(f16x8*)&Klds[buf][kr * KSTRIDE + ((kt8 ^ sw_) * 8)]       = koA.v;  \
    *(f16x8*)&Klds[buf][kr * KSTRIDE + (((kt8 + 8) ^ sw_) * 8)] = koB.v;  \
    _Pragma("unroll")                                                     \
    for (int ci = 0; ci < 8; ++ci) {                                      \
      const float e0 = (ci < 4 ? pv0[ci] : pv1[ci - 4]);                  \
      const float e1 = (ci < 4 ? pv2[ci] : pv3[ci - 4]);                  \
      const float e2 = (ci < 4 ? pv4[ci] : pv5[ci - 4]);                  \
      const float e3 = (ci < 4 ? pv6[ci] : pv7[ci - 4]);                  \
      union { h16x2 a2[2]; f16x4 v; } t;                                  \
      t.a2[0] = __builtin_amdgcn_cvt_pkrtz(e0, e1);                       \
      t.a2[1] = __builtin_amdgcn_cvt_pkrtz(e2, e3);                       \
      *(f16x4*)&Vlds[buf][(vc0 + ci) * VSTRIDE + ((kblk ^ vsw) * 8) + (inb ^ vflip)] = t.v; \
    }                                                                     \
  } while (0)

  for (int half = 0; half < 2; ++half) {
    const int qt = half ? qpair : (7 - qpair);   // heavy q-tile first
    const int wq0 = qt * QTILE + w * 32;         // wave's lowest q-row
    const int qgr = wq0 + l31;                   // this lane's q-row

    LOADT(0);   // prologue: tile 0 data loads in flight during Q prep

    // ---- Q -> registers as 32x32x16 B-frags (RoPE'd, pre-scaled by log2e) ----
    f16x8 qfrag[8];
    {
      const float* qp = xq + (row0 + qgr) * (size_t)(NHEAD * ZDIM) + h * ZDIM;
      const float* cq = cosT + qgr * (ZDIM / 2);
      const float* sq = sinT + qgr * (ZDIM / 2);
#pragma unroll
      for (int dblk = 0; dblk < 8; ++dblk) {
        const int d0 = dblk * 16 + hi * 8;
        f32x4 a  = *(const f32x4*)(qp + d0);
        f32x4 b2 = *(const f32x4*)(qp + d0 + 4);
        f32x4 cv = *(const f32x4*)(cq + (d0 >> 1));
        f32x4 sv = *(const f32x4*)(sq + (d0 >> 1));
        union { h16x2 h2[4]; f16x8 v; } fr;
#pragma unroll
        for (int p = 0; p < 4; ++p) {
          const float xr = (p < 2 ? a[2 * p] : b2[2 * p - 4]);
          const float xi = (p < 2 ? a[2 * p + 1] : b2[2 * p - 3]);
          fr.h2[p] = __builtin_amdgcn_cvt_pkrtz((xr * cv[p] - xi * sv[p]) * LOG2E,
                                                (xr * sv[p] + xi * cv[p]) * LOG2E);
        }
        qfrag[dblk] = fr.v;
      }
    }

    const f32x16 zf = {};
    f32x16 acc[8];
#pragma unroll
    for (int g = 0; g < 8; ++g) acc[g] = zf;
    float mrun = -1e30f;
    float lrun = 0.f;

    const int nkt = 4 * (qt + 1);

    for (int kt = 0; kt < nkt; ++kt) {
      const int ktb = kt * KT;

      // ---- cvt+write tile kt from prefetched regs; issue tile kt+1 loads ----
      WRITET(ktb);
      if (kt + 1 < nkt) LOADT(ktb + KT);   // in flight under this tile's compute
      __syncthreads();                     // staged tile visible

      if (ktb <= wq0 + 31) {
        // ---- S^T = K Q : col=l31=q, row=k-local ----
        f32x16 s = {};
        __builtin_amdgcn_s_setprio(1);
#pragma unroll
        for (int dblk = 0; dblk < 8; ++dblk) {
          f16x8 kf = *(const f16x8*)&Klds[buf][l31 * KSTRIDE + (((dblk * 2 + hi) ^ kswz) * 8)];
          s = __builtin_amdgcn_mfma_f32_32x32x16_f16(kf, qfrag[dblk], s, 0, 0, 0);
        }
        __builtin_amdgcn_s_setprio(0);

        // ---- causal mask (partial tiles only); k_local = (r&3)+8*(r>>2)+4*hi ----
        if (ktb + 31 > wq0) {
#pragma unroll
          for (int r = 0; r < 16; ++r) {
            const int kg = ktb + ((r & 3) + 8 * (r >> 2) + 4 * hi);
            if (kg > qgr) s[r] = -1.0e9f;
          }
        }

        // ---- softmax: lane-local max + one cross-half shuffle ----
        float m = s[0];
#pragma unroll
        for (int r = 1; r < 16; ++r) m = fmaxf(m, s[r]);
        m = fmaxf(m, __shfl_xor(m, 32));
        const bool need = (m > mrun + RTHR);
        if (__any(need)) {
          const float Mn = fmaxf(mrun, m);
          const float al = exp2f(mrun - Mn);
          mrun = Mn;
          lrun *= al;
#pragma unroll
          for (int r = 0; r < 16; ++r) {
            const float alr = __shfl(al, (r & 3) + 8 * (r >> 2) + 4 * hi);
#pragma unroll
            for (int g = 0; g < 8; ++g) acc[g][r] *= alr;
          }
        }
        float lsum = 0.f;
#pragma unroll
        for (int r = 0; r < 16; ++r) {
          s[r] = exp2f(s[r] - mrun);
          lsum += s[r];
        }
        lrun += lsum;

        // ---- P -> fp16 A-frags in registers, then PV ----
#pragma unroll
        for (int kb = 0; kb < 2; ++kb) {
          union { h16x2 h; u32 u; } A_, B_, C_, D_;
          A_.h = __builtin_amdgcn_cvt_pkrtz(s[8 * kb + 0], s[8 * kb + 1]);
          B_.h = __builtin_amdgcn_cvt_pkrtz(s[8 * kb + 2], s[8 * kb + 3]);
          C_.h = __builtin_amdgcn_cvt_pkrtz(s[8 * kb + 4], s[8 * kb + 5]);
          D_.h = __builtin_amdgcn_cvt_pkrtz(s[8 * kb + 6], s[8 * kb + 7]);
          const u32 G1 = hi ? A_.u : C_.u;
          const u32 G2 = hi ? B_.u : D_.u;
          const u32 G1s = (u32)__shfl_xor((int)G1, 32);
          const u32 G2s = (u32)__shfl_xor((int)G2, 32);
          union { u32 u[4]; f16x8 v; } af;
          af.u[0] = hi ? G1s : A_.u;
          af.u[1] = hi ? G2s : B_.u;
          af.u[2] = hi ? C_.u : G1s;
          af.u[3] = hi ? D_.u : G2s;
          __builtin_amdgcn_s_setprio(1);
#pragma unroll
          for (int g = 0; g < 8; ++g) {
            const int vcol = g * 32 + l31;
            const int ck = (((kb * 2 + hi) ^ vswz) * 8);
            const int fl = (g & 1) * 4;   // matches write-side (vcol>>5)&1
            union { f16x4 h4[2]; f16x8 v; } bf;
            bf.h4[0] = *(const f16x4*)&Vlds[buf][vcol * VSTRIDE + ck + fl];
            bf.h4[1] = *(const f16x4*)&Vlds[buf][vcol * VSTRIDE + ck + (fl ^ 4)];
            acc[g] = __builtin_amdgcn_mfma_f32_32x32x16_f16(af.v, bf.v, acc[g], 0, 0, 0);
          }
          __builtin_amdgcn_s_setprio(0);
        }
      }
      buf ^= 1;
    }

    // ---- epilogue: denom reduce (1 shuffle), per-row linv broadcast, store ----
    const float ls = lrun + __shfl_xor(lrun, 32);
    const float linv = 1.0f / ls;
#pragma unroll
    for (int r = 0; r < 16; ++r) {
      const int qloc = (r & 3) + 8 * (r >> 2) + 4 * hi;
      const float lr = __shfl(linv, qloc);
      const size_t ob = (row0 + wq0 + qloc) * (size_t)(NHEAD * VDIM) + h * VDIM + l31;
#pragma unroll
      for (int g = 0; g < 8; ++g)
        out[ob + g * 32] = acc[g][r] * lr;
    }
    __syncthreads();   // half boundary: all reads done before next half restages
  }
#undef LOADT
#undef WRITET
}

extern "C" void kernel_launch(void* const* d_in, const int* in_sizes, int n_in,
                              void* d_out, int out_size, void* d_ws, size_t ws_size,
                              hipStream_t stream) {
  const float* xq   = (const float*)d_in[0];
  const float* xk   = (const float*)d_in[1];
  const float* xv   = (const float*)d_in[2];
  // d_in[3] = mask (unused: causal mask computed analytically)
  const float* cosT = (const float*)d_in[4];
  const float* sinT = (const float*)d_in[5];
  float* out = (float*)d_out;

  dim3 grid(512);    // (4 qpairs) x (128 chunk*head), XCD-swizzled, 2 blocks/CU
  dim3 block(256);   // 4 waves
  attn_fused<<<grid, block, 0, stream>>>(xq, xk, xv, cosT, sinT, out);
}

// Round 14
// 184.152 us; speedup vs baseline: 1.4585x; 1.4585x over previous
//
#include <hip/hip_runtime.h>

// Fused chunked causal attention + RoPE for MI355X (gfx950).
// B=4, SLEN=4096, H=8, ZD=128, VD=256, CHUNK=1024 -> 16 chunks x 8 heads.
// fp32 in/out; fp16 MFMA 32x32x16, fp32 accum.
// Round 14: r9 verbatim (proven 182us) + ONE change: V staging threads own
// columns strided by 32 (col = (tid&31)+32j) instead of 8 consecutive.
// Store addr = 18*lane mod 32 -> conflict-free V writes (was structural
// 8-way: 16*lane+18*ci mod 32 hits 2 slots). Loads stay coalesced (scalar,
// lane-consecutive). Read side & all math identical to r9.

#define NHEAD 8
#define ZDIM  128
#define VDIM  256
#define CHUNK 1024
#define QTILE 128   // q rows per block (4 waves x 32)
#define KT    32    // k rows per tile
#define NW    4

typedef _Float16 f16x8 __attribute__((ext_vector_type(8)));
typedef _Float16 f16x4 __attribute__((ext_vector_type(4)));
typedef __fp16   h16x2 __attribute__((ext_vector_type(2)));   // cvt_pkrtz return type
typedef float    f32x4  __attribute__((ext_vector_type(4)));
typedef float    f32x16 __attribute__((ext_vector_type(16)));
typedef unsigned int u32;

#define KSTRIDE 128   // halfs per K-lds row (256B rows; chunk^(row&7) XOR swizzle)
#define VSTRIDE 36    // halfs per V^T-lds row (32 + 4 pad)
#define LOG2E   1.44269504088896f
#define RTHR    11.5415603f   /* 8 nats in log2 domain: defer-max threshold */

__global__ __launch_bounds__(256, 2)
void attn_fused(const float* __restrict__ xq, const float* __restrict__ xk,
                const float* __restrict__ xv, const float* __restrict__ cosT,
                const float* __restrict__ sinT, float* __restrict__ out)
{
  __shared__ _Float16 Klds[2][KT * KSTRIDE];     // 16.0 KB
  __shared__ _Float16 Vlds[2][VDIM * VSTRIDE];   // 36.9 KB (transposed, swizzled)
  // total 52.9 KB -> 2 blocks/CU (register-limited to 2 anyway)

  // XCD-grouping swizzle (bijective on [0,512))
  const int b = (int)blockIdx.x;
  const int d = (b & 7) * 64 + (b >> 3);
  const int qpair = d & 3;                       // 0..3 -> q-tiles {7-qpair, qpair}
  const int ch = d >> 2;                         // 0..127
  const int h  = ch & 7;
  const int cb = ch >> 3;

  const int tid  = threadIdx.x;
  const int w    = tid >> 6;                     // wave 0..3
  const int lane = tid & 63;
  const int l31  = lane & 31;
  const int hi   = lane >> 5;                    // 0/1
  const int vswz = (l31 >> 3) & 3;               // V read kblk XOR
  const int kswz = l31 & 7;                      // K read chunk XOR (row&7)

  const size_t row0 = (size_t)cb * CHUNK;

  // staging thread mapping
  const int kr    = tid >> 3;             // K row 0..31
  const int kt8   = tid & 7;              // K chunk pair {kt8, kt8+8}
  const int vgr   = tid >> 5;             // 0..7 -> V rows vgr*4..+3
  const int vcl   = tid & 31;             // V base col; owns cols vcl+32j, j=0..7
  const int vsw2  = (vcl >> 3) & 3;       // = (col>>3)&3 (same for all j)
  const int kblk  = vgr >> 1;
  const int inb   = (vgr & 1) * 4;

  int buf = 0;

  for (int half = 0; half < 2; ++half) {
    const int qt = half ? qpair : (7 - qpair);   // heavy q-tile first
    const int wq0 = qt * QTILE + w * 32;         // wave's lowest q-row
    const int qgr = wq0 + l31;                   // this lane's q-row

    // ---- Q -> registers as 32x32x16 B-frags (RoPE'd, pre-scaled by log2e) ----
    f16x8 qfrag[8];
    {
      const float* qp = xq + (row0 + qgr) * (size_t)(NHEAD * ZDIM) + h * ZDIM;
      const float* cq = cosT + qgr * (ZDIM / 2);
      const float* sq = sinT + qgr * (ZDIM / 2);
#pragma unroll
      for (int dblk = 0; dblk < 8; ++dblk) {
        const int d0 = dblk * 16 + hi * 8;
        f32x4 a  = *(const f32x4*)(qp + d0);
        f32x4 b2 = *(const f32x4*)(qp + d0 + 4);
        f32x4 cv = *(const f32x4*)(cq + (d0 >> 1));
        f32x4 sv = *(const f32x4*)(sq + (d0 >> 1));
        union { h16x2 h2[4]; f16x8 v; } fr;
#pragma unroll
        for (int p = 0; p < 4; ++p) {
          const float xr = (p < 2 ? a[2 * p] : b2[2 * p - 4]);
          const float xi = (p < 2 ? a[2 * p + 1] : b2[2 * p - 3]);
          fr.h2[p] = __builtin_amdgcn_cvt_pkrtz((xr * cv[p] - xi * sv[p]) * LOG2E,
                                                (xr * sv[p] + xi * cv[p]) * LOG2E);
        }
        qfrag[dblk] = fr.v;
      }
    }

    const f32x16 zf = {};
    f32x16 acc[8];
#pragma unroll
    for (int g = 0; g < 8; ++g) acc[g] = zf;
    float mrun = -1e30f;
    float lrun = 0.f;

    const int nkt = 4 * (qt + 1);

    for (int kt = 0; kt < nkt; ++kt) {
      const int ktb = kt * KT;
      // ---- stage K tile with RoPE -> Klds[buf]; chunks {kt8, kt8+8}, slot = c^(kr&7) ----
      {
        const int krow = ktb + kr;
        const float* kpb = xk + (row0 + krow) * (size_t)(NHEAD * ZDIM) + h * ZDIM;
        const float* ckb = cosT + krow * (ZDIM / 2);
        const float* skb = sinT + krow * (ZDIM / 2);
        f32x4 a0 = *(const f32x4*)(kpb + 8 * kt8);
        f32x4 a1 = *(const f32x4*)(kpb + 8 * kt8 + 4);
        f32x4 ca = *(const f32x4*)(ckb + 4 * kt8);
        f32x4 sa = *(const f32x4*)(skb + 4 * kt8);
        f32x4 b0 = *(const f32x4*)(kpb + 8 * kt8 + 64);
        f32x4 b1 = *(const f32x4*)(kpb + 8 * kt8 + 68);
        f32x4 cbv = *(const f32x4*)(ckb + 4 * kt8 + 32);
        f32x4 sbv = *(const f32x4*)(skb + 4 * kt8 + 32);
        union { h16x2 h2[4]; f16x8 v; } koA, koB;
#pragma unroll
        for (int p = 0; p < 4; ++p) {
          const float xrA = (p < 2 ? a0[2 * p] : a1[2 * p - 4]);
          const float xiA = (p < 2 ? a0[2 * p + 1] : a1[2 * p - 3]);
          koA.h2[p] = __builtin_amdgcn_cvt_pkrtz(xrA * ca[p] - xiA * sa[p],
                                                 xrA * sa[p] + xiA * ca[p]);
          const float xrB = (p < 2 ? b0[2 * p] : b1[2 * p - 4]);
          const float xiB = (p < 2 ? b0[2 * p + 1] : b1[2 * p - 3]);
          koB.h2[p] = __builtin_amdgcn_cvt_pkrtz(xrB * cbv[p] - xiB * sbv[p],
                                                 xrB * sbv[p] + xiB * cbv[p]);
        }
        const int sw = kr & 7;
        *(f16x8*)&Klds[buf][kr * KSTRIDE + ((kt8 ^ sw) * 8)]       = koA.v;
        *(f16x8*)&Klds[buf][kr * KSTRIDE + (((kt8 + 8) ^ sw) * 8)] = koB.v;
      }
      // ---- stage V tile transposed -> Vlds[buf]; cols vcl+32j (conflict-free writes) ----
      {
        const int vrow = ktb + vgr * 4;
        const float* vp = xv + (row0 + vrow) * (size_t)(NHEAD * VDIM) + h * VDIM + vcl;
        float e0[8], e1[8], e2[8], e3[8];
#pragma unroll
        for (int j = 0; j < 8; ++j) {
          e0[j] = vp[32 * j];
          e1[j] = vp[2048 + 32 * j];
          e2[j] = vp[4096 + 32 * j];
          e3[j] = vp[6144 + 32 * j];
        }
#pragma unroll
        for (int j = 0; j < 8; ++j) {
          union { h16x2 a2[2]; f16x4 v; } t;
          t.a2[0] = __builtin_amdgcn_cvt_pkrtz(e0[j], e1[j]);
          t.a2[1] = __builtin_amdgcn_cvt_pkrtz(e2[j], e3[j]);
          *(f16x4*)&Vlds[buf][(vcl + 32 * j) * VSTRIDE + ((kblk ^ vsw2) * 8) + (inb ^ ((j & 1) * 4))] = t.v;
        }
      }
      __syncthreads();   // staging visible; dbuf makes one barrier/tile safe

      // ---- per-wave skip of fully-masked tiles ----
      if (ktb <= wq0 + 31) {
        // ---- S^T = K Q : col=l31=q, row=k-local ----
        f32x16 s = {};
        __builtin_amdgcn_s_setprio(1);
#pragma unroll
        for (int dblk = 0; dblk < 8; ++dblk) {
          f16x8 kf = *(const f16x8*)&Klds[buf][l31 * KSTRIDE + (((dblk * 2 + hi) ^ kswz) * 8)];
          s = __builtin_amdgcn_mfma_f32_32x32x16_f16(kf, qfrag[dblk], s, 0, 0, 0);
        }
        __builtin_amdgcn_s_setprio(0);

        // ---- causal mask (partial tiles only); k_local = (r&3)+8*(r>>2)+4*hi ----
        if (ktb + 31 > wq0) {
#pragma unroll
          for (int r = 0; r < 16; ++r) {
            const int kg = ktb + ((r & 3) + 8 * (r >> 2) + 4 * hi);
            if (kg > qgr) s[r] = -1.0e9f;
          }
        }

        // ---- softmax: lane-local max + one cross-half shuffle ----
        float m = s[0];
#pragma unroll
        for (int r = 1; r < 16; ++r) m = fmaxf(m, s[r]);
        m = fmaxf(m, __shfl_xor(m, 32));
        const bool need = (m > mrun + RTHR);
        if (__any(need)) {
          const float Mn = fmaxf(mrun, m);
          const float al = exp2f(mrun - Mn);
          mrun = Mn;
          lrun *= al;
#pragma unroll
          for (int r = 0; r < 16; ++r) {
            const float alr = __shfl(al, (r & 3) + 8 * (r >> 2) + 4 * hi);
#pragma unroll
            for (int g = 0; g < 8; ++g) acc[g][r] *= alr;
          }
        }
        float lsum = 0.f;
#pragma unroll
        for (int r = 0; r < 16; ++r) {
          s[r] = exp2f(s[r] - mrun);
          lsum += s[r];
        }
        lrun += lsum;

        // ---- P -> fp16 A-frags in registers, then PV ----
#pragma unroll
        for (int kb = 0; kb < 2; ++kb) {
          union { h16x2 h; u32 u; } A_, B_, C_, D_;
          A_.h = __builtin_amdgcn_cvt_pkrtz(s[8 * kb + 0], s[8 * kb + 1]);
          B_.h = __builtin_amdgcn_cvt_pkrtz(s[8 * kb + 2], s[8 * kb + 3]);
          C_.h = __builtin_amdgcn_cvt_pkrtz(s[8 * kb + 4], s[8 * kb + 5]);
          D_.h = __builtin_amdgcn_cvt_pkrtz(s[8 * kb + 6], s[8 * kb + 7]);
          const u32 G1 = hi ? A_.u : C_.u;
          const u32 G2 = hi ? B_.u : D_.u;
          const u32 G1s = (u32)__shfl_xor((int)G1, 32);
          const u32 G2s = (u32)__shfl_xor((int)G2, 32);
          union { u32 u[4]; f16x8 v; } af;
          af.u[0] = hi ? G1s : A_.u;
          af.u[1] = hi ? G2s : B_.u;
          af.u[2] = hi ? C_.u : G1s;
          af.u[3] = hi ? D_.u : G2s;
          __builtin_amdgcn_s_setprio(1);
#pragma unroll
          for (int g = 0; g < 8; ++g) {
            const int vcol = g * 32 + l31;
            const int ck = (((kb * 2 + hi) ^ vswz) * 8);
            const int fl = (g & 1) * 4;   // matches write-side (col>>5)&1 = j&1
            union { f16x4 h4[2]; f16x8 v; } bf;
            bf.h4[0] = *(const f16x4*)&Vlds[buf][vcol * VSTRIDE + ck + fl];
            bf.h4[1] = *(const f16x4*)&Vlds[buf][vcol * VSTRIDE + ck + (fl ^ 4)];
            acc[g] = __builtin_amdgcn_mfma_f32_32x32x16_f16(af.v, bf.v, acc[g], 0, 0, 0);
          }
          __builtin_amdgcn_s_setprio(0);
        }
      }
      buf ^= 1;
    }

    // ---- epilogue: denom reduce (1 shuffle), per-row linv broadcast, store ----
    const float ls = lrun + __shfl_xor(lrun, 32);
    const float linv = 1.0f / ls;
#pragma unroll
    for (int r = 0; r < 16; ++r) {
      const int qloc = (r & 3) + 8 * (r >> 2) + 4 * hi;
      const float lr = __shfl(linv, qloc);
      const size_t ob = (row0 + wq0 + qloc) * (size_t)(NHEAD * VDIM) + h * VDIM + l31;
#pragma unroll
      for (int g = 0; g < 8; ++g)
        out[ob + g * 32] = acc[g][r] * lr;
    }
    __syncthreads();   // half boundary: all reads done before next half restages
  }
}

extern "C" void kernel_launch(void* const* d_in, const int* in_sizes, int n_in,
                              void* d_out, int out_size, void* d_ws, size_t ws_size,
                              hipStream_t stream) {
  const float* xq   = (const float*)d_in[0];
  const float* xk   = (const float*)d_in[1];
  const float* xv   = (const float*)d_in[2];
  // d_in[3] = mask (unused: causal mask computed analytically)
  const float* cosT = (const float*)d_in[4];
  const float* sinT = (const float*)d_in[5];
  float* out = (float*)d_out;

  dim3 grid(512);    // (4 qpairs) x (128 chunk*head), XCD-swizzled, 2 blocks/CU
  dim3 block(256);   // 4 waves
  attn_fused<<<grid, block, 0, stream>>>(xq, xk, xv, cosT, sinT, out);
}